// Round 24
// baseline (122.477 us; speedup 1.0000x reference)
//
#include <hip/hip_runtime.h>
#include <hip/hip_bf16.h>

typedef __bf16 bf16;
typedef __bf16 bf16x8 __attribute__((ext_vector_type(8)));
typedef __bf16 bf16x4 __attribute__((ext_vector_type(4)));
typedef float f32x4 __attribute__((ext_vector_type(4)));

#define MFMA16(a, b, c) __builtin_amdgcn_mfma_f32_16x16x32_bf16((a), (b), (c), 0, 0, 0)

constexpr int S = 4096;
constexpr int E = 1024;
constexpr int H = 16;
constexpr int HD = 64;
constexpr float NEG = -1e30f;
// scores in log2 domain: fold 1/sqrt(64) * log2(e) into Q
constexpr float QSCALE = 0.125f * 1.44269504088896f;

__device__ inline bf16x8 load_f32x8_as_bf16(const float* __restrict__ p) {
  float4 u0 = *reinterpret_cast<const float4*>(p);
  float4 u1 = *reinterpret_cast<const float4*>(p + 4);
  bf16x8 r;
  r[0] = (bf16)u0.x; r[1] = (bf16)u0.y; r[2] = (bf16)u0.z; r[3] = (bf16)u0.w;
  r[4] = (bf16)u1.x; r[5] = (bf16)u1.y; r[6] = (bf16)u1.z; r[7] = (bf16)u1.w;
  return r;
}

// ---------------- QKV projection (+ wo->bf16 folded in as blockIdx.y == 16) ----------------
// 128 s-rows per block (R23-verified). Q pre-scaled; V stored transposed vt[h][d][s].
__global__ __launch_bounds__(256) void qkv_cvt_kernel(
    const float* __restrict__ x, const float* __restrict__ wq,
    const float* __restrict__ wk, const float* __restrict__ wv,
    const float* __restrict__ wo,
    bf16* __restrict__ qb, bf16* __restrict__ kb, bf16* __restrict__ vt,
    bf16* __restrict__ wob) {
  if (blockIdx.y == 16) {  // wo -> bf16 conversion lane
    for (int i = (blockIdx.x * 256 + threadIdx.x) * 4; i < E * E; i += 32 * 256 * 4) {
      float4 f = *reinterpret_cast<const float4*>(wo + i);
      bf16x4 b;
      b[0] = (bf16)f.x; b[1] = (bf16)f.y; b[2] = (bf16)f.z; b[3] = (bf16)f.w;
      *reinterpret_cast<bf16x4*>(wob + i) = b;
    }
    return;
  }
  const int h = blockIdx.y;
  const int s0 = blockIdx.x * 128;
  const int w = threadIdx.x >> 6;
  const int l = threadIdx.x & 63;
  const int lg = l >> 4, lr = l & 15;

  bf16x8 af[2][2];  // [half][ks]
#pragma unroll
  for (int half = 0; half < 2; ++half) {
    const float* xp = x + (size_t)(s0 + half * 64 + w * 16 + lr) * E + h * HD;
    af[half][0] = load_f32x8_as_bf16(xp + lg * 8);
    af[half][1] = load_f32x8_as_bf16(xp + 32 + lg * 8);
  }
  const float* Wsrc[3] = {wq + (size_t)h * HD * HD, wk + (size_t)h * HD * HD,
                          wv + (size_t)h * HD * HD};
#pragma unroll
  for (int pj = 0; pj < 3; ++pj) {
    f32x4 acc[2][4];
#pragma unroll
    for (int half = 0; half < 2; ++half)
#pragma unroll
      for (int ot = 0; ot < 4; ++ot) acc[half][ot] = f32x4{0.f, 0.f, 0.f, 0.f};
#pragma unroll
    for (int ks = 0; ks < 2; ++ks) {
#pragma unroll
      for (int ot = 0; ot < 4; ++ot) {
        bf16x8 bfr = load_f32x8_as_bf16(Wsrc[pj] + (size_t)(ot * 16 + lr) * HD + ks * 32 + lg * 8);
        acc[0][ot] = MFMA16(af[0][ks], bfr, acc[0][ot]);
        acc[1][ot] = MFMA16(af[1][ks], bfr, acc[1][ot]);
      }
    }
#pragma unroll
    for (int half = 0; half < 2; ++half) {
      const int sb = s0 + half * 64;
      if (pj == 2) {
#pragma unroll
        for (int ot = 0; ot < 4; ++ot) {
          bf16x4 b;
#pragma unroll
          for (int r = 0; r < 4; ++r) b[r] = (bf16)acc[half][ot][r];
          *reinterpret_cast<bf16x4*>(vt + (size_t)(h * HD + ot * 16 + lr) * S +
                                     sb + w * 16 + lg * 4) = b;
        }
      } else {
        const float scale = (pj == 0) ? QSCALE : 1.0f;
        bf16* op = ((pj == 0) ? qb : kb) + (size_t)h * S * HD;
#pragma unroll
        for (int ot = 0; ot < 4; ++ot)
#pragma unroll
          for (int r = 0; r < 4; ++r)
            op[(size_t)(sb + w * 16 + lg * 4 + r) * HD + ot * 16 + lr] =
                (bf16)(acc[half][ot][r] * scale);
      }
    }
  }
}

// ---------------- causal flash attention: MFMA16, 2-D wave split, 16 KB single-buffer LDS ----------------
// R21/R23 math byte-identical; LDS halved to 16 KB (KVl[0]=K, KVl[1]=V, single
// buffer) so 4 blocks/CU can co-reside (occupancy evidence says the effective
// LDS pool is ~64 KB). Two barriers per stage: (reads done) -> swrite -> (writes
// visible); gload(st+1) issued before compute so load latency hides under it.
// Merge epilogue repacked into the 16 KB buffer in two u-phases.
__global__ __launch_bounds__(256, 4) void attn_kernel(
    const bf16* __restrict__ qb, const bf16* __restrict__ kb,
    const bf16* __restrict__ vt, bf16* __restrict__ ob) {
  __shared__ bf16 KVl[2][64 * 64];  // [0]=K rows, [1]=V^T rows; 16 KB total
  const int b = blockIdx.x;
  const int xcd = b & 7;
  const int idx = b >> 3;                    // 0..127
  const int p = idx >> 1, hb = idx & 1;
  const int head = 2 * xcd + hb;
  const int qt = (p < 32) ? (hb ? p : 63 - p) : (hb ? 95 - p : p - 32);
  const int tid = threadIdx.x;
  const int w = tid >> 6, l = tid & 63;
  const int qc = l & 15, h = l >> 4;         // q-col in tile, lane group
  const int i = w & 1, j = w >> 1;           // q-half, kv-half
  const int j32 = j * 32;
  const int q0w = qt * 64 + i * 32;
  const int nst = qt + 1;                    // 64-kv stages, block-uniform
  const int sw = (qc & 7) << 3;              // XOR swizzle

  bf16x8 qf[2][2];  // [u][c]: col q = q0w + u*16 + qc, k(d) = c*32 + h*8 + ii
  {
    const bf16* qp = qb + ((size_t)head * S + q0w + qc) * HD + h * 8;
    qf[0][0] = *reinterpret_cast<const bf16x8*>(qp);
    qf[0][1] = *reinterpret_cast<const bf16x8*>(qp + 32);
    qf[1][0] = *reinterpret_cast<const bf16x8*>(qp + 16 * HD);
    qf[1][1] = *reinterpret_cast<const bf16x8*>(qp + 16 * HD + 32);
  }
  const bf16* kbase = kb + (size_t)head * S * HD;
  const bf16* vbase = vt + (size_t)head * HD * S;

  f32x4 acc[2][4];  // [u][dt]: O^T col q = (u,qc), row d = 16*dt + 4*h + r
#pragma unroll
  for (int u = 0; u < 2; ++u)
#pragma unroll
    for (int dt = 0; dt < 4; ++dt) acc[u][dt] = f32x4{0.f, 0.f, 0.f, 0.f};
  float m0 = NEG, m1 = NEG, l0 = 0.f, l1 = 0.f;

  // staging: 256 threads x 2 granules each for K and V (16B granules)
  auto gload = [&](int st, bf16x8 (&kr)[2], bf16x8 (&vr)[2]) {
    const int kv0 = st * 64;
#pragma unroll
    for (int jj = 0; jj < 2; ++jj) {
      const int g = tid + jj * 256;
      const int row = g >> 3, ge = g & 7;
      kr[jj] = *reinterpret_cast<const bf16x8*>(kbase + (size_t)(kv0 + row) * HD + ge * 8);
      vr[jj] = *reinterpret_cast<const bf16x8*>(vbase + (size_t)row * S + kv0 + ge * 8);
    }
  };
  auto swrite = [&](bf16x8 (&kr)[2], bf16x8 (&vr)[2]) {
#pragma unroll
    for (int jj = 0; jj < 2; ++jj) {
      const int g = tid + jj * 256;
      const int row = g >> 3, ge = g & 7;
      const int off = row * 64 + ((ge * 8) ^ ((row & 7) << 3));
      *reinterpret_cast<bf16x8*>(&KVl[0][off]) = kr[jj];
      *reinterpret_cast<bf16x8*>(&KVl[1][off]) = vr[jj];
    }
  };

  bf16x8 kr[2], vr[2];
  gload(0, kr, vr);
  swrite(kr, vr);
  __syncthreads();

  for (int st = 0; st < nst; ++st) {
    const int kv0 = st * 64;
    const bool pre = (st + 1 < nst);
    if (pre) gload(st + 1, kr, vr);  // issue early; landed by swrite after compute

    if (kv0 + j32 <= q0w + 31) {  // wave's kv chunk fully masked? skip (exact)
      // --- S^T: A-frag = K rows (j32+16t+qc), k(d)=c*32+h*8 -> 4 LDS reads ---
      bf16x8 kf[2][2];
#pragma unroll
      for (int t = 0; t < 2; ++t)
#pragma unroll
        for (int c = 0; c < 2; ++c)
          kf[t][c] = *reinterpret_cast<const bf16x8*>(
              &KVl[0][(j32 + 16 * t + qc) * 64 + ((c * 32 + h * 8) ^ sw)]);
      f32x4 sv[2][2];  // [u][t]
      __builtin_amdgcn_s_setprio(1);
#pragma unroll
      for (int u = 0; u < 2; ++u)
#pragma unroll
        for (int t = 0; t < 2; ++t) {
          f32x4 a = f32x4{0.f, 0.f, 0.f, 0.f};
          a = MFMA16(kf[t][0], qf[u][0], a);
          a = MFMA16(kf[t][1], qf[u][1], a);
          sv[u][t] = a;
        }
      __builtin_amdgcn_s_setprio(0);
      // --- V frags for PV (4 reads, shared across both u) ---
      bf16x8 vf[4];
#pragma unroll
      for (int dt = 0; dt < 4; ++dt)
        vf[dt] = *reinterpret_cast<const bf16x8*>(
            &KVl[1][(16 * dt + qc) * 64 + ((j32 + h * 8) ^ sw)]);
      // --- causal mask: kv = kv0+j32+16t+4h+r vs q = q0w+u*16+qc ---
      if (kv0 + 63 > q0w) {
#pragma unroll
        for (int u = 0; u < 2; ++u) {
          const int q = q0w + u * 16 + qc;
#pragma unroll
          for (int t = 0; t < 2; ++t)
#pragma unroll
            for (int r = 0; r < 4; ++r)
              if (kv0 + j32 + 16 * t + 4 * h + r > q) sv[u][t][r] = NEG;
        }
      }
      // --- online softmax (log2 domain, defer-max thr=8), per q-half u ---
      float t0 = NEG, t1 = NEG;
#pragma unroll
      for (int t = 0; t < 2; ++t)
#pragma unroll
        for (int r = 0; r < 4; ++r) {
          t0 = fmaxf(t0, sv[0][t][r]);
          t1 = fmaxf(t1, sv[1][t][r]);
        }
      if (!__all((t0 <= m0 + 8.f) && (t1 <= m1 + 8.f))) {
        float a0 = fmaxf(t0, __shfl_xor(t0, 16));
        a0 = fmaxf(a0, __shfl_xor(a0, 32));
        float a1 = fmaxf(t1, __shfl_xor(t1, 16));
        a1 = fmaxf(a1, __shfl_xor(a1, 32));
        float mn0 = fmaxf(m0, a0), mn1 = fmaxf(m1, a1);
        float al0 = exp2f(m0 - mn0), al1 = exp2f(m1 - mn1);
        l0 *= al0; l1 *= al1;
#pragma unroll
        for (int dt = 0; dt < 4; ++dt)
#pragma unroll
          for (int r = 0; r < 4; ++r) {
            acc[0][dt][r] *= al0;
            acc[1][dt][r] *= al1;
          }
        m0 = mn0; m1 = mn1;
      }
      float p0 = 0.f, p1 = 0.f;
#pragma unroll
      for (int t = 0; t < 2; ++t)
#pragma unroll
        for (int r = 0; r < 4; ++r) {
          float d0 = sv[0][t][r] - m0, e0;
          asm("v_exp_f32 %0, %1" : "=v"(e0) : "v"(d0));
          sv[0][t][r] = e0; p0 += e0;
          float d1 = sv[1][t][r] - m1, e1;
          asm("v_exp_f32 %0, %1" : "=v"(e1) : "v"(d1));
          sv[1][t][r] = e1; p1 += e1;
        }
      l0 += p0; l1 += p1;
      // --- P->bf16, permlane exchange (R19 mapping, per u), PV ---
#pragma unroll
      for (int u = 0; u < 2; ++u) {
        union { unsigned u32; bf16 h2[2]; } pa, pb;
        unsigned x0, x1, y0, y1;
        pa.h2[0] = (bf16)sv[u][0][0]; pa.h2[1] = (bf16)sv[u][0][1]; x0 = pa.u32;
        pb.h2[0] = (bf16)sv[u][0][2]; pb.h2[1] = (bf16)sv[u][0][3]; x1 = pb.u32;
        pa.h2[0] = (bf16)sv[u][1][0]; pa.h2[1] = (bf16)sv[u][1][1]; y0 = pa.u32;
        pb.h2[0] = (bf16)sv[u][1][2]; pb.h2[1] = (bf16)sv[u][1][3]; y1 = pb.u32;
        asm("v_permlane32_swap_b32 %0, %1" : "+v"(x0), "+v"(y0));
        asm("v_permlane16_swap_b32 %0, %1" : "+v"(x0), "+v"(y0));
        asm("v_permlane32_swap_b32 %0, %1" : "+v"(x1), "+v"(y1));
        asm("v_permlane16_swap_b32 %0, %1" : "+v"(x1), "+v"(y1));
        union { bf16x8 v; unsigned uu[4]; } B;
        B.uu[0] = x0; B.uu[1] = x1; B.uu[2] = y0; B.uu[3] = y1;
        __builtin_amdgcn_s_setprio(1);
#pragma unroll
        for (int dt = 0; dt < 4; ++dt) acc[u][dt] = MFMA16(vf[dt], B.v, acc[u][dt]);
        __builtin_amdgcn_s_setprio(0);
      }
    }
    // --- all reads done; overwrite the single buffer with next stage ---
    __syncthreads();
    if (pre) {
      swrite(kr, vr);
      __syncthreads();
    }
  }

  // --- reduce l across h-groups (per q-column) ---
  float lt0 = l0 + __shfl_xor(l0, 16); lt0 += __shfl_xor(lt0, 32);
  float lt1 = l1 + __shfl_xor(l1, 16); lt1 += __shfl_xor(lt1, 32);

  // --- exact merge of kv-half j=1 into j=0, two u-phases, via the 16 KB buffer ---
  float* fb = (float*)KVl;  // 4096 floats: [0,2048) acc slots (i,dt,h,r,qc); [2048,2112) (m,l)
  __syncthreads();          // main-loop reads fully drained before reuse
#pragma unroll
  for (int u = 0; u < 2; ++u) {
    if (j == 1) {
#pragma unroll
      for (int dt = 0; dt < 4; ++dt)
#pragma unroll
        for (int r = 0; r < 4; ++r)
          fb[(((i * 4 + dt) * 4 + h) * 4 + r) * 16 + qc] = acc[u][dt][r];
      if (h == 0) {
        fb[2048 + (i * 16 + qc) * 2] = (u == 0) ? m0 : m1;
        fb[2048 + (i * 16 + qc) * 2 + 1] = (u == 0) ? lt0 : lt1;
      }
    }
    __syncthreads();
    if (j == 0) {
      const float mA = (u == 0) ? m0 : m1;
      const float lA = (u == 0) ? lt0 : lt1;
      const float mB = fb[2048 + (i * 16 + qc) * 2];
      const float lB = fb[2048 + (i * 16 + qc) * 2 + 1];
      const float M = fmaxf(mA, mB);
      const float eA = exp2f(mA - M), eB = exp2f(mB - M);
      const float inv = 1.0f / (eA * lA + eB * lB);
      bf16* obp = ob + (size_t)(q0w + u * 16 + qc) * E + head * HD;
#pragma unroll
      for (int dt = 0; dt < 4; ++dt) {
        bf16x4 bb;
#pragma unroll
        for (int r = 0; r < 4; ++r) {
          float vB = fb[(((i * 4 + dt) * 4 + h) * 4 + r) * 16 + qc];
          bb[r] = (bf16)((eA * acc[u][dt][r] + eB * vB) * inv);
        }
        *reinterpret_cast<bf16x4*>(obp + 16 * dt + 4 * h) = bb;
      }
    }
    __syncthreads();
  }
}

// ---------------- output projection: out = attn @ wo^T, 128x128 tiles, B in LDS (R20-verified) ----------------
__global__ __launch_bounds__(256) void out_gemm_kernel(
    const bf16* __restrict__ ob, const bf16* __restrict__ wob,
    float* __restrict__ out) {
  __shared__ bf16 Bl[2][128 * 64];  // [buf][col*64 + swizzled kk]  (2 x 16 KB)
  const int tid = threadIdx.x;
  const int w = tid >> 6, l = tid & 63, lg = l >> 4, lr = l & 15;
  const int s0 = blockIdx.x * 128, e0 = blockIdx.y * 128;
  f32x4 acc[2][8];
#pragma unroll
  for (int rt = 0; rt < 2; ++rt)
#pragma unroll
    for (int ct = 0; ct < 8; ++ct) acc[rt][ct] = f32x4{0.f, 0.f, 0.f, 0.f};
  const bf16* ap0 = ob + (size_t)(s0 + w * 32 + lr) * E;
  const bf16* ap1 = ap0 + (size_t)16 * E;

  auto gloadB = [&](int k0, bf16x8 (&br)[4]) {
#pragma unroll
    for (int jj = 0; jj < 4; ++jj) {
      const int g = tid + jj * 256;
      const int col = g >> 3, ge = g & 7;
      br[jj] = *reinterpret_cast<const bf16x8*>(wob + (size_t)(e0 + col) * E + k0 + ge * 8);
    }
  };
  auto swriteB = [&](int buf, bf16x8 (&br)[4]) {
#pragma unroll
    for (int jj = 0; jj < 4; ++jj) {
      const int g = tid + jj * 256;
      const int col = g >> 3, ge = g & 7;
      *reinterpret_cast<bf16x8*>(&Bl[buf][col * 64 + ((ge * 8) ^ ((col & 7) << 3))]) = br[jj];
    }
  };

  bf16x8 br[4];
  gloadB(0, br);
  swriteB(0, br);
  __syncthreads();

  for (int it = 0; it < 16; ++it) {
    const int k0 = it * 64;
    const int buf = it & 1;
    const bool pre = (it + 1 < 16);
    if (pre) gloadB(k0 + 64, br);  // issue early; landed by swriteB at iter end

    bf16x8 af[2][2];
#pragma unroll
    for (int ks = 0; ks < 2; ++ks) {
      af[0][ks] = *reinterpret_cast<const bf16x8*>(ap0 + k0 + ks * 32 + lg * 8);
      af[1][ks] = *reinterpret_cast<const bf16x8*>(ap1 + k0 + ks * 32 + lg * 8);
    }
#pragma unroll
    for (int ks = 0; ks < 2; ++ks)
#pragma unroll
      for (int ct = 0; ct < 8; ++ct) {
        bf16x8 bfr = *reinterpret_cast<const bf16x8*>(
            &Bl[buf][(ct * 16 + lr) * 64 + ((ks * 32 + lg * 8) ^ ((lr & 7) << 3))]);
        acc[0][ct] = MFMA16(af[0][ks], bfr, acc[0][ct]);
        acc[1][ct] = MFMA16(af[1][ks], bfr, acc[1][ct]);
      }
    if (pre) swriteB(buf ^ 1, br);
    __syncthreads();
  }

#pragma unroll
  for (int rt = 0; rt < 2; ++rt)
#pragma unroll
    for (int ct = 0; ct < 8; ++ct)
#pragma unroll
      for (int r = 0; r < 4; ++r)
        out[(size_t)(s0 + w * 32 + rt * 16 + lg * 4 + r) * E + e0 + ct * 16 + lr] =
            acc[rt][ct][r];
}

extern "C" void kernel_launch(void* const* d_in, const int* in_sizes, int n_in,
                              void* d_out, int out_size, void* d_ws, size_t ws_size,
                              hipStream_t stream) {
  const float* x  = (const float*)d_in[0];
  const float* wq = (const float*)d_in[1];
  const float* wk = (const float*)d_in[2];
  const float* wv = (const float*)d_in[3];
  const float* wo = (const float*)d_in[4];
  float* out = (float*)d_out;

  bf16* qb  = (bf16*)d_ws;                 // [H][S][HD]
  bf16* kb  = qb + (size_t)H * S * HD;     // [H][S][HD]
  bf16* vt  = kb + (size_t)H * S * HD;     // [H][HD][S]  (V transposed)
  bf16* ob  = vt + (size_t)H * S * HD;     // [S][E]
  bf16* wob = ob + (size_t)S * E;          // [E][E]

  qkv_cvt_kernel<<<dim3(S / 128, H + 1), 256, 0, stream>>>(x, wq, wk, wv, wo, qb, kb, vt, wob);
  attn_kernel<<<dim3(1024), 256, 0, stream>>>(qb, kb, vt, ob);
  out_gemm_kernel<<<dim3(S / 128, E / 128), 256, 0, stream>>>(ob, wob, out);
}

// Round 25
// 117.551 us; speedup vs baseline: 1.0419x; 1.0419x over previous
//
#include <hip/hip_runtime.h>
#include <hip/hip_bf16.h>

typedef __bf16 bf16;
typedef __bf16 bf16x8 __attribute__((ext_vector_type(8)));
typedef __bf16 bf16x4 __attribute__((ext_vector_type(4)));
typedef float f32x4 __attribute__((ext_vector_type(4)));

#define MFMA16(a, b, c) __builtin_amdgcn_mfma_f32_16x16x32_bf16((a), (b), (c), 0, 0, 0)

constexpr int S = 4096;
constexpr int E = 1024;
constexpr int H = 16;
constexpr int HD = 64;
constexpr float NEG = -1e30f;
// scores in log2 domain: fold 1/sqrt(64) * log2(e) into Q
constexpr float QSCALE = 0.125f * 1.44269504088896f;

__device__ inline bf16x8 load_f32x8_as_bf16(const float* __restrict__ p) {
  float4 u0 = *reinterpret_cast<const float4*>(p);
  float4 u1 = *reinterpret_cast<const float4*>(p + 4);
  bf16x8 r;
  r[0] = (bf16)u0.x; r[1] = (bf16)u0.y; r[2] = (bf16)u0.z; r[3] = (bf16)u0.w;
  r[4] = (bf16)u1.x; r[5] = (bf16)u1.y; r[6] = (bf16)u1.z; r[7] = (bf16)u1.w;
  return r;
}

// ---------------- QKV projection (+ wo->bf16 folded in as blockIdx.y == 16) ----------------
// 128 s-rows per block: W fragments loaded once per pj serve both 64-row halves
// (2x MFMA per W byte, half the W L2 traffic, half the launch count).
// Q pre-scaled by QSCALE; V written TRANSPOSED: vt[h][d][s]
__global__ __launch_bounds__(256) void qkv_cvt_kernel(
    const float* __restrict__ x, const float* __restrict__ wq,
    const float* __restrict__ wk, const float* __restrict__ wv,
    const float* __restrict__ wo,
    bf16* __restrict__ qb, bf16* __restrict__ kb, bf16* __restrict__ vt,
    bf16* __restrict__ wob) {
  if (blockIdx.y == 16) {  // wo -> bf16 conversion lane
    for (int i = (blockIdx.x * 256 + threadIdx.x) * 4; i < E * E; i += 32 * 256 * 4) {
      float4 f = *reinterpret_cast<const float4*>(wo + i);
      bf16x4 b;
      b[0] = (bf16)f.x; b[1] = (bf16)f.y; b[2] = (bf16)f.z; b[3] = (bf16)f.w;
      *reinterpret_cast<bf16x4*>(wob + i) = b;
    }
    return;
  }
  const int h = blockIdx.y;
  const int s0 = blockIdx.x * 128;
  const int w = threadIdx.x >> 6;
  const int l = threadIdx.x & 63;
  const int lg = l >> 4, lr = l & 15;

  bf16x8 af[2][2];  // [half][ks]
#pragma unroll
  for (int half = 0; half < 2; ++half) {
    const float* xp = x + (size_t)(s0 + half * 64 + w * 16 + lr) * E + h * HD;
    af[half][0] = load_f32x8_as_bf16(xp + lg * 8);
    af[half][1] = load_f32x8_as_bf16(xp + 32 + lg * 8);
  }
  const float* Wsrc[3] = {wq + (size_t)h * HD * HD, wk + (size_t)h * HD * HD,
                          wv + (size_t)h * HD * HD};
#pragma unroll
  for (int pj = 0; pj < 3; ++pj) {
    f32x4 acc[2][4];
#pragma unroll
    for (int half = 0; half < 2; ++half)
#pragma unroll
      for (int ot = 0; ot < 4; ++ot) acc[half][ot] = f32x4{0.f, 0.f, 0.f, 0.f};
#pragma unroll
    for (int ks = 0; ks < 2; ++ks) {
#pragma unroll
      for (int ot = 0; ot < 4; ++ot) {
        bf16x8 bfr = load_f32x8_as_bf16(Wsrc[pj] + (size_t)(ot * 16 + lr) * HD + ks * 32 + lg * 8);
        acc[0][ot] = MFMA16(af[0][ks], bfr, acc[0][ot]);
        acc[1][ot] = MFMA16(af[1][ks], bfr, acc[1][ot]);
      }
    }
#pragma unroll
    for (int half = 0; half < 2; ++half) {
      const int sb = s0 + half * 64;
      if (pj == 2) {
        // V^T store: vt[(h*HD + o)][s]
#pragma unroll
        for (int ot = 0; ot < 4; ++ot) {
          bf16x4 b;
#pragma unroll
          for (int r = 0; r < 4; ++r) b[r] = (bf16)acc[half][ot][r];
          *reinterpret_cast<bf16x4*>(vt + (size_t)(h * HD + ot * 16 + lr) * S +
                                     sb + w * 16 + lg * 4) = b;
        }
      } else {
        const float scale = (pj == 0) ? QSCALE : 1.0f;
        bf16* op = ((pj == 0) ? qb : kb) + (size_t)h * S * HD;
#pragma unroll
        for (int ot = 0; ot < 4; ++ot)
#pragma unroll
          for (int r = 0; r < 4; ++r)
            op[(size_t)(sb + w * 16 + lg * 4 + r) * HD + ot * 16 + lr] =
                (bf16)(acc[half][ot][r] * scale);
      }
    }
  }
}

// ---------------- causal flash attention: MFMA16, 2-D wave split (R21-verified, byte-identical) ----------------
__global__ __launch_bounds__(256, 4) void attn_kernel(
    const bf16* __restrict__ qb, const bf16* __restrict__ kb,
    const bf16* __restrict__ vt, bf16* __restrict__ ob) {
  __shared__ bf16 Kl[2][64 * 64];  // [buf][kv-row][d-col swizzled]; epilogue: acc merge (4096 f32)
  __shared__ bf16 Vl[2][64 * 64];  // [buf][d-row][kv-col swizzled]; epilogue: (m,l) slots
  const int b = blockIdx.x;
  const int xcd = b & 7;
  const int idx = b >> 3;                    // 0..127
  const int p = idx >> 1, hb = idx & 1;
  const int head = 2 * xcd + hb;
  const int qt = (p < 32) ? (hb ? p : 63 - p) : (hb ? 95 - p : p - 32);
  const int tid = threadIdx.x;
  const int w = tid >> 6, l = tid & 63;
  const int qc = l & 15, h = l >> 4;         // q-col in tile, lane group
  const int i = w & 1, j = w >> 1;           // q-half, kv-half
  const int j32 = j * 32;
  const int q0w = qt * 64 + i * 32;
  const int nst = qt + 1;                    // 64-kv stages, block-uniform
  const int sw = (qc & 7) << 3;              // XOR swizzle (row&7 == qc&7 for all rows used)

  bf16x8 qf[2][2];  // [u][c]: col q = q0w + u*16 + qc, k(d) = c*32 + h*8 + ii
  {
    const bf16* qp = qb + ((size_t)head * S + q0w + qc) * HD + h * 8;
    qf[0][0] = *reinterpret_cast<const bf16x8*>(qp);
    qf[0][1] = *reinterpret_cast<const bf16x8*>(qp + 32);
    qf[1][0] = *reinterpret_cast<const bf16x8*>(qp + 16 * HD);
    qf[1][1] = *reinterpret_cast<const bf16x8*>(qp + 16 * HD + 32);
  }
  const bf16* kbase = kb + (size_t)head * S * HD;
  const bf16* vbase = vt + (size_t)head * HD * S;

  f32x4 acc[2][4];  // [u][dt]: O^T col q = (u,qc), row d = 16*dt + 4*h + r
#pragma unroll
  for (int u = 0; u < 2; ++u)
#pragma unroll
    for (int dt = 0; dt < 4; ++dt) acc[u][dt] = f32x4{0.f, 0.f, 0.f, 0.f};
  float m0 = NEG, m1 = NEG, l0 = 0.f, l1 = 0.f;

  // staging: 256 threads x 2 granules each for K and V (16B granules)
  auto gload = [&](int st, bf16x8 (&kr)[2], bf16x8 (&vr)[2]) {
    const int kv0 = st * 64;
#pragma unroll
    for (int jj = 0; jj < 2; ++jj) {
      const int g = tid + jj * 256;
      const int row = g >> 3, ge = g & 7;
      kr[jj] = *reinterpret_cast<const bf16x8*>(kbase + (size_t)(kv0 + row) * HD + ge * 8);
      vr[jj] = *reinterpret_cast<const bf16x8*>(vbase + (size_t)row * S + kv0 + ge * 8);
    }
  };
  auto swrite = [&](int buf, bf16x8 (&kr)[2], bf16x8 (&vr)[2]) {
#pragma unroll
    for (int jj = 0; jj < 2; ++jj) {
      const int g = tid + jj * 256;
      const int row = g >> 3, ge = g & 7;
      const int off = row * 64 + ((ge * 8) ^ ((row & 7) << 3));
      *reinterpret_cast<bf16x8*>(&Kl[buf][off]) = kr[jj];
      *reinterpret_cast<bf16x8*>(&Vl[buf][off]) = vr[jj];
    }
  };

  bf16x8 kr[2], vr[2];
  gload(0, kr, vr);
  swrite(0, kr, vr);
  __syncthreads();

  for (int st = 0; st < nst; ++st) {
    const int buf = st & 1;
    const int kv0 = st * 64;
    const bool pre = (st + 1 < nst);
    if (pre) gload(st + 1, kr, vr);  // issue early; consumed by swrite at stage end

    if (kv0 + j32 <= q0w + 31) {  // wave's kv chunk fully masked? skip (exact)
      // --- S^T: A-frag = K rows (j32+16t+qc), k(d)=c*32+h*8 -> 4 LDS reads ---
      bf16x8 kf[2][2];
#pragma unroll
      for (int t = 0; t < 2; ++t)
#pragma unroll
        for (int c = 0; c < 2; ++c)
          kf[t][c] = *reinterpret_cast<const bf16x8*>(
              &Kl[buf][(j32 + 16 * t + qc) * 64 + ((c * 32 + h * 8) ^ sw)]);
      f32x4 sv[2][2];  // [u][t]
      __builtin_amdgcn_s_setprio(1);
#pragma unroll
      for (int u = 0; u < 2; ++u)
#pragma unroll
        for (int t = 0; t < 2; ++t) {
          f32x4 a = f32x4{0.f, 0.f, 0.f, 0.f};
          a = MFMA16(kf[t][0], qf[u][0], a);
          a = MFMA16(kf[t][1], qf[u][1], a);
          sv[u][t] = a;
        }
      __builtin_amdgcn_s_setprio(0);
      // --- V frags for PV (4 reads, shared across both u) ---
      bf16x8 vf[4];
#pragma unroll
      for (int dt = 0; dt < 4; ++dt)
        vf[dt] = *reinterpret_cast<const bf16x8*>(
            &Vl[buf][(16 * dt + qc) * 64 + ((j32 + h * 8) ^ sw)]);
      // --- causal mask: kv = kv0+j32+16t+4h+r vs q = q0w+u*16+qc ---
      if (kv0 + 63 > q0w) {
#pragma unroll
        for (int u = 0; u < 2; ++u) {
          const int q = q0w + u * 16 + qc;
#pragma unroll
          for (int t = 0; t < 2; ++t)
#pragma unroll
            for (int r = 0; r < 4; ++r)
              if (kv0 + j32 + 16 * t + 4 * h + r > q) sv[u][t][r] = NEG;
        }
      }
      // --- online softmax (log2 domain, defer-max thr=8), per q-half u ---
      float t0 = NEG, t1 = NEG;
#pragma unroll
      for (int t = 0; t < 2; ++t)
#pragma unroll
        for (int r = 0; r < 4; ++r) {
          t0 = fmaxf(t0, sv[0][t][r]);
          t1 = fmaxf(t1, sv[1][t][r]);
        }
      if (!__all((t0 <= m0 + 8.f) && (t1 <= m1 + 8.f))) {
        float a0 = fmaxf(t0, __shfl_xor(t0, 16));
        a0 = fmaxf(a0, __shfl_xor(a0, 32));
        float a1 = fmaxf(t1, __shfl_xor(t1, 16));
        a1 = fmaxf(a1, __shfl_xor(a1, 32));
        float mn0 = fmaxf(m0, a0), mn1 = fmaxf(m1, a1);
        float al0 = exp2f(m0 - mn0), al1 = exp2f(m1 - mn1);
        l0 *= al0; l1 *= al1;
#pragma unroll
        for (int dt = 0; dt < 4; ++dt)
#pragma unroll
          for (int r = 0; r < 4; ++r) {
            acc[0][dt][r] *= al0;
            acc[1][dt][r] *= al1;
          }
        m0 = mn0; m1 = mn1;
      }
      float p0 = 0.f, p1 = 0.f;
#pragma unroll
      for (int t = 0; t < 2; ++t)
#pragma unroll
        for (int r = 0; r < 4; ++r) {
          float d0 = sv[0][t][r] - m0, e0;
          asm("v_exp_f32 %0, %1" : "=v"(e0) : "v"(d0));
          sv[0][t][r] = e0; p0 += e0;
          float d1 = sv[1][t][r] - m1, e1;
          asm("v_exp_f32 %0, %1" : "=v"(e1) : "v"(d1));
          sv[1][t][r] = e1; p1 += e1;
        }
      l0 += p0; l1 += p1;
      // --- P->bf16, permlane exchange (R19 mapping, per u), PV ---
#pragma unroll
      for (int u = 0; u < 2; ++u) {
        union { unsigned u32; bf16 h2[2]; } pa, pb;
        unsigned x0, x1, y0, y1;
        pa.h2[0] = (bf16)sv[u][0][0]; pa.h2[1] = (bf16)sv[u][0][1]; x0 = pa.u32;
        pb.h2[0] = (bf16)sv[u][0][2]; pb.h2[1] = (bf16)sv[u][0][3]; x1 = pb.u32;
        pa.h2[0] = (bf16)sv[u][1][0]; pa.h2[1] = (bf16)sv[u][1][1]; y0 = pa.u32;
        pb.h2[0] = (bf16)sv[u][1][2]; pb.h2[1] = (bf16)sv[u][1][3]; y1 = pb.u32;
        asm("v_permlane32_swap_b32 %0, %1" : "+v"(x0), "+v"(y0));
        asm("v_permlane16_swap_b32 %0, %1" : "+v"(x0), "+v"(y0));
        asm("v_permlane32_swap_b32 %0, %1" : "+v"(x1), "+v"(y1));
        asm("v_permlane16_swap_b32 %0, %1" : "+v"(x1), "+v"(y1));
        union { bf16x8 v; unsigned uu[4]; } B;
        B.uu[0] = x0; B.uu[1] = x1; B.uu[2] = y0; B.uu[3] = y1;
        __builtin_amdgcn_s_setprio(1);
#pragma unroll
        for (int dt = 0; dt < 4; ++dt) acc[u][dt] = MFMA16(vf[dt], B.v, acc[u][dt]);
        __builtin_amdgcn_s_setprio(0);
      }
    }
    // --- write next stage's tiles into the other buffer; lockstep barrier ---
    if (pre) swrite(buf ^ 1, kr, vr);
    __syncthreads();
  }

  // --- reduce l across h-groups (per q-column) ---
  float lt0 = l0 + __shfl_xor(l0, 16); lt0 += __shfl_xor(lt0, 32);
  float lt1 = l1 + __shfl_xor(l1, 16); lt1 += __shfl_xor(lt1, 32);

  // --- exact merge of kv-half j=1 into j=0 through dead K/V LDS ---
  float* fK = (float*)Kl;  // 4096 floats: slot(i,u,dt,h,r,qc)
  float* fV = (float*)Vl;  // (m,l) per (i,u,qc)
  if (j == 1) {
#pragma unroll
    for (int u = 0; u < 2; ++u) {
#pragma unroll
      for (int dt = 0; dt < 4; ++dt)
#pragma unroll
        for (int r = 0; r < 4; ++r)
          fK[((((i * 2 + u) * 4 + dt) * 4 + h) * 4 + r) * 16 + qc] = acc[u][dt][r];
      if (h == 0) {
        fV[((i * 2 + u) * 16 + qc) * 2] = (u == 0) ? m0 : m1;
        fV[((i * 2 + u) * 16 + qc) * 2 + 1] = (u == 0) ? lt0 : lt1;
      }
    }
  }
  __syncthreads();
  if (j == 0) {
#pragma unroll
    for (int u = 0; u < 2; ++u) {
      const float mA = (u == 0) ? m0 : m1;
      const float lA = (u == 0) ? lt0 : lt1;
      const float mB = fV[((i * 2 + u) * 16 + qc) * 2];
      const float lB = fV[((i * 2 + u) * 16 + qc) * 2 + 1];
      const float M = fmaxf(mA, mB);
      const float eA = exp2f(mA - M), eB = exp2f(mB - M);
      const float inv = 1.0f / (eA * lA + eB * lB);
      bf16* obp = ob + (size_t)(q0w + u * 16 + qc) * E + head * HD;
#pragma unroll
      for (int dt = 0; dt < 4; ++dt) {
        bf16x4 bb;
#pragma unroll
        for (int r = 0; r < 4; ++r) {
          float vB = fK[((((i * 2 + u) * 4 + dt) * 4 + h) * 4 + r) * 16 + qc];
          bb[r] = (bf16)((eA * acc[u][dt][r] + eB * vB) * inv);
        }
        *reinterpret_cast<bf16x4*>(obp + 16 * dt + 4 * h) = bb;
      }
    }
  }
}

// ---------------- output projection: out = attn @ wo^T, 128x128 tiles, B in LDS (R20-verified) ----------------
__global__ __launch_bounds__(256) void out_gemm_kernel(
    const bf16* __restrict__ ob, const bf16* __restrict__ wob,
    float* __restrict__ out) {
  __shared__ bf16 Bl[2][128 * 64];  // [buf][col*64 + swizzled kk]  (2 x 16 KB)
  const int tid = threadIdx.x;
  const int w = tid >> 6, l = tid & 63, lg = l >> 4, lr = l & 15;
  const int s0 = blockIdx.x * 128, e0 = blockIdx.y * 128;
  f32x4 acc[2][8];
#pragma unroll
  for (int rt = 0; rt < 2; ++rt)
#pragma unroll
    for (int ct = 0; ct < 8; ++ct) acc[rt][ct] = f32x4{0.f, 0.f, 0.f, 0.f};
  const bf16* ap0 = ob + (size_t)(s0 + w * 32 + lr) * E;
  const bf16* ap1 = ap0 + (size_t)16 * E;

  auto gloadB = [&](int k0, bf16x8 (&br)[4]) {
#pragma unroll
    for (int jj = 0; jj < 4; ++jj) {
      const int g = tid + jj * 256;
      const int col = g >> 3, ge = g & 7;
      br[jj] = *reinterpret_cast<const bf16x8*>(wob + (size_t)(e0 + col) * E + k0 + ge * 8);
    }
  };
  auto swriteB = [&](int buf, bf16x8 (&br)[4]) {
#pragma unroll
    for (int jj = 0; jj < 4; ++jj) {
      const int g = tid + jj * 256;
      const int col = g >> 3, ge = g & 7;
      *reinterpret_cast<bf16x8*>(&Bl[buf][col * 64 + ((ge * 8) ^ ((col & 7) << 3))]) = br[jj];
    }
  };

  bf16x8 br[4];
  gloadB(0, br);
  swriteB(0, br);
  __syncthreads();

  for (int it = 0; it < 16; ++it) {
    const int k0 = it * 64;
    const int buf = it & 1;
    const bool pre = (it + 1 < 16);
    if (pre) gloadB(k0 + 64, br);  // issue early; landed by swriteB at iter end

    bf16x8 af[2][2];
#pragma unroll
    for (int ks = 0; ks < 2; ++ks) {
      af[0][ks] = *reinterpret_cast<const bf16x8*>(ap0 + k0 + ks * 32 + lg * 8);
      af[1][ks] = *reinterpret_cast<const bf16x8*>(ap1 + k0 + ks * 32 + lg * 8);
    }
#pragma unroll
    for (int ks = 0; ks < 2; ++ks)
#pragma unroll
      for (int ct = 0; ct < 8; ++ct) {
        bf16x8 bfr = *reinterpret_cast<const bf16x8*>(
            &Bl[buf][(ct * 16 + lr) * 64 + ((ks * 32 + lg * 8) ^ ((lr & 7) << 3))]);
        acc[0][ct] = MFMA16(af[0][ks], bfr, acc[0][ct]);
        acc[1][ct] = MFMA16(af[1][ks], bfr, acc[1][ct]);
      }
    if (pre) swriteB(buf ^ 1, br);
    __syncthreads();
  }

#pragma unroll
  for (int rt = 0; rt < 2; ++rt)
#pragma unroll
    for (int ct = 0; ct < 8; ++ct)
#pragma unroll
      for (int r = 0; r < 4; ++r)
        out[(size_t)(s0 + w * 32 + rt * 16 + lg * 4 + r) * E + e0 + ct * 16 + lr] =
            acc[rt][ct][r];
}

extern "C" void kernel_launch(void* const* d_in, const int* in_sizes, int n_in,
                              void* d_out, int out_size, void* d_ws, size_t ws_size,
                              hipStream_t stream) {
  const float* x  = (const float*)d_in[0];
  const float* wq = (const float*)d_in[1];
  const float* wk = (const float*)d_in[2];
  const float* wv = (const float*)d_in[3];
  const float* wo = (const float*)d_in[4];
  float* out = (float*)d_out;

  bf16* qb  = (bf16*)d_ws;                 // [H][S][HD]
  bf16* kb  = qb + (size_t)H * S * HD;     // [H][S][HD]
  bf16* vt  = kb + (size_t)H * S * HD;     // [H][HD][S]  (V transposed)
  bf16* ob  = vt + (size_t)H * S * HD;     // [S][E]
  bf16* wob = ob + (size_t)S * E;          // [E][E]

  qkv_cvt_kernel<<<dim3(S / 128, H + 1), 256, 0, stream>>>(x, wq, wk, wv, wo, qb, kb, vt, wob);
  attn_kernel<<<dim3(1024), 256, 0, stream>>>(qb, kb, vt, ob);
  out_gemm_kernel<<<dim3(S / 128, E / 128), 256, 0, stream>>>(ob, wob, out);
}